// Round 15
// baseline (161.870 us; speedup 1.0000x reference)
//
#include <hip/hip_runtime.h>

typedef _Float16 f16;
typedef f16  f16x8 __attribute__((ext_vector_type(8)));
typedef float f32x4 __attribute__((ext_vector_type(4)));

#define NPTS 4096
#define HW   24576
#define WID  192
#define CH   128

// ---- workspace layout (bytes) ----
#define OFF_NNIDX   (0u)           // int[49152]
#define OFF_CORR    (196608u)      // float[49152]
#define OFF_SAMPLED (393216u)      // float[8192*128]
#define OFF_F3T     (4587520u)     // float[8192*128]
#define OFF_WHL     (8781824u)     // f16[3][2][128][128]  (layer, hi/lo)
// total 8978432 bytes (~9 MB)

// Split weights into f16 hi/lo pairs: w = wh + wl (+ O(5e-4^2) dropped).
// Layer-1 uses only the 128 feat3d columns (w1 cols 3..130); the 3
// offset/corr columns are applied exactly in f32 in the conv epilogue.
__global__ __launch_bounds__(256) void k_prep_w(const float* __restrict__ w1,
                                                const float* __restrict__ w2,
                                                const float* __restrict__ w3,
                                                f16* __restrict__ whl) {
  int i = blockIdx.x * 256 + threadIdx.x;   // 3*16384
  if (i >= 49152) return;
  int layer = i >> 14;
  int r = i & 16383;
  int o = r >> 7, k = r & 127;
  float v;
  if (layer == 0)      v = w1[o * 131 + 3 + k];
  else if (layer == 1) v = w2[o * 128 + k];
  else                 v = w3[o * 128 + k];
  f16 h = (f16)v;
  f16 l = (f16)(v - (float)h);
  whl[(layer * 2 + 0) * 16384 + r] = h;
  whl[(layer * 2 + 1) * 16384 + r] = l;
}

// Bilinear sample feat_2d at all points -> sampled[b][p][c] (f32),
// and transpose feat_3d -> f3t[b][p][c] (f32).
__global__ __launch_bounds__(256) void k_sample(const float* __restrict__ uv,
                                                const float* __restrict__ feat2d,
                                                const float* __restrict__ feat3d,
                                                float* __restrict__ sampled,
                                                float* __restrict__ f3t) {
  int pid = blockIdx.x * 2 + (threadIdx.x >> 7);   // 0..8191
  int c = threadIdx.x & 127;
  int b = pid >> 12;
  int p = pid & (NPTS - 1);
  const float* up = uv + b * 2 * NPTS;
  float u = up[p], v = up[NPTS + p];
  float x0f = floorf(u), y0f = floorf(v);
  float wx = u - x0f, wy = v - y0f;
  int x0 = (int)x0f; x0 = min(max(x0, 0), WID - 1);
  int x1 = min(x0 + 1, WID - 1);
  int y0 = (int)y0f; y0 = min(max(y0, 0), 127);
  int y1 = min(y0 + 1, 127);
  const float* fp = feat2d + (size_t)(b * CH + c) * HW;
  float g00 = fp[y0 * WID + x0], g01 = fp[y0 * WID + x1];
  float g10 = fp[y1 * WID + x0], g11 = fp[y1 * WID + x1];
  float s = g00 * (1.f - wx) * (1.f - wy) + g01 * wx * (1.f - wy)
          + g10 * (1.f - wx) * wy + g11 * wx * wy;
  sampled[(size_t)(b * NPTS + p) * CH + c] = s;
  f3t[(size_t)(b * NPTS + p) * CH + c] = feat3d[(size_t)(b * CH + c) * NPTS + p];
}

// Argmin, faithful-numpy form (THE untested matrix cell):
//   qp  = fma(y, v, RN(x*u))   <-- np.einsum C loop: acc = fma(g_d,u_d,acc),
//                                  k-ascending (ffp-contract=on contraction)
//   ssu = RN(RN(u*u)+RN(v*v))  <-- uv*uv materialized ufunc, then pairwise sum
//   d2  = RN(RN(ssg - RN(2*qp)) + ssu)   (left-to-right, V1)
// Every op pinned with asm barriers + contract(off) so hipcc cannot re-fold.
// First-index ties: strict-< ascending scan + ascending quarter merge.
__global__ __launch_bounds__(256) void k_nn(const float* __restrict__ uv,
                                            int* __restrict__ nn_idx) {
#pragma clang fp contract(off)
  __shared__ float2 uvs[NPTS];
  __shared__ float  ssus[NPTS];
  __shared__ float  bd[4][64];
  __shared__ int    bis[4][64];
  int blk = blockIdx.x;              // 768 = 2 batches * 384
  int b = blk / 384;
  int q0 = (blk - b * 384) * 64;
  const float* up = uv + b * 2 * NPTS;
  for (int p = threadIdx.x; p < NPTS; p += 256) {
    float u = up[p], v = up[NPTS + p];
    uvs[p] = make_float2(u, v);
    float uu = u * u;   asm volatile("" : "+v"(uu));
    float vv = v * v;   asm volatile("" : "+v"(vv));
    float ss = uu + vv; asm volatile("" : "+v"(ss));
    ssus[p] = ss;
  }
  __syncthreads();
  int px = threadIdx.x & 63;
  int qt = threadIdx.x >> 6;         // point-quarter
  int q = q0 + px;
  float xq = (float)(q % WID);
  float yq = (float)(q / WID);
  float ssg = xq * xq + yq * yq;     // exact (integers < 2^24)
  float best = 3.4e38f; int bi = 0;
  int pbeg = qt * 1024, pend = pbeg + 1024;
  for (int p = pbeg; p < pend; ++p) {
    float2 t = uvs[p];
    float xu = xq * t.x;                       asm volatile("" : "+v"(xu));
    float qp = __builtin_fmaf(yq, t.y, xu);    asm volatile("" : "+v"(qp));
    float tq = 2.0f * qp;                      asm volatile("" : "+v"(tq));
    float t1 = ssg - tq;                       asm volatile("" : "+v"(t1));
    float d2 = t1 + ssus[p];                   asm volatile("" : "+v"(d2));
    if (d2 < best) { best = d2; bi = p; }
  }
  bd[qt][px] = best; bis[qt][px] = bi;
  __syncthreads();
  if (qt == 0) {
    #pragma unroll
    for (int k = 1; k < 4; ++k) {
      float d = bd[k][px];
      if (d < best) { best = d; bi = bis[k][px]; }  // strict < keeps earliest idx
    }
    nn_idx[b * HW + q] = bi;
  }
}

// corr[q] = mean_c sampled[j][c] * feat2d[c][q]   (f32)
__global__ __launch_bounds__(256) void k_corr(const int* __restrict__ nn_idx,
                                              const float* __restrict__ sampled,
                                              const float* __restrict__ feat2d,
                                              float* __restrict__ corr) {
  __shared__ float part[4][64];
  int blk = blockIdx.x;
  int b = blk / 384;
  int q0 = (blk - b * 384) * 64;
  int px = threadIdx.x & 63;
  int cg = threadIdx.x >> 6;
  int q = q0 + px;
  int j = nn_idx[b * HW + q];
  const float* sp = sampled + (size_t)(b * NPTS + j) * CH + cg * 32;
  const float* f2 = feat2d + (size_t)(b * CH + cg * 32) * HW + q;
  float acc = 0.f;
  #pragma unroll 8
  for (int i = 0; i < 32; ++i) acc += sp[i] * f2[(size_t)i * HW];
  part[cg][px] = acc;
  __syncthreads();
  if (cg == 0) {
    float s = (part[0][px] + part[1][px]) + (part[2][px] + part[3][px]);
    corr[b * HW + q] = s * 0.0078125f;
  }
}

// One conv layer via split-f16 MFMA: acc += Wh*xh + Wh*xl + Wl*xh, f32 accum.
// buf: f32 [64 px][132]; in-place (write y over k<128 after barrier).
template<bool LAYER1, bool LAST>
__device__ __forceinline__ void conv_layer(float* buf, const f16* wh, const f16* wl,
                                           const float* bias, const float* w1full,
                                           float* og, int wv, int l15, int l4) {
  f32x4 acc[2][4];
  #pragma unroll
  for (int r = 0; r < 2; ++r)
    #pragma unroll
    for (int c = 0; c < 4; ++c) acc[r][c] = (f32x4){0.f, 0.f, 0.f, 0.f};

  for (int k0 = 0; k0 < 128; k0 += 32) {
    f16x8 ah0 = *(const f16x8*)&wh[(wv * 32 + l15) * 128 + k0 + l4 * 8];
    f16x8 ah1 = *(const f16x8*)&wh[(wv * 32 + 16 + l15) * 128 + k0 + l4 * 8];
    f16x8 al0 = *(const f16x8*)&wl[(wv * 32 + l15) * 128 + k0 + l4 * 8];
    f16x8 al1 = *(const f16x8*)&wl[(wv * 32 + 16 + l15) * 128 + k0 + l4 * 8];
    #pragma unroll
    for (int c = 0; c < 4; ++c) {
      const float* bp = &buf[(c * 16 + l15) * 132 + k0 + l4 * 8];
      f32x4 v0 = *(const f32x4*)bp;
      f32x4 v1 = *(const f32x4*)(bp + 4);
      f16x8 bh, bl;
      #pragma unroll
      for (int i = 0; i < 4; ++i) {
        float x = v0[i]; f16 h = (f16)x; bh[i] = h; bl[i] = (f16)(x - (float)h);
        float x2 = v1[i]; f16 h2 = (f16)x2; bh[4 + i] = h2; bl[4 + i] = (f16)(x2 - (float)h2);
      }
      acc[0][c] = __builtin_amdgcn_mfma_f32_16x16x32_f16(ah0, bh, acc[0][c], 0, 0, 0);
      acc[0][c] = __builtin_amdgcn_mfma_f32_16x16x32_f16(ah0, bl, acc[0][c], 0, 0, 0);
      acc[0][c] = __builtin_amdgcn_mfma_f32_16x16x32_f16(al0, bh, acc[0][c], 0, 0, 0);
      acc[1][c] = __builtin_amdgcn_mfma_f32_16x16x32_f16(ah1, bh, acc[1][c], 0, 0, 0);
      acc[1][c] = __builtin_amdgcn_mfma_f32_16x16x32_f16(ah1, bl, acc[1][c], 0, 0, 0);
      acc[1][c] = __builtin_amdgcn_mfma_f32_16x16x32_f16(al1, bh, acc[1][c], 0, 0, 0);
    }
  }
  __syncthreads();   // all reads of buf done before in-place overwrite
  #pragma unroll
  for (int r = 0; r < 2; ++r) {
    int ob = wv * 32 + r * 16 + l4 * 4;
    f32x4 bb = *(const f32x4*)&bias[ob];
    float w1c[4][3];
    if (LAYER1) {
      #pragma unroll
      for (int e = 0; e < 4; ++e) {
        w1c[e][0] = w1full[(ob + e) * 131 + 0];
        w1c[e][1] = w1full[(ob + e) * 131 + 1];
        w1c[e][2] = w1full[(ob + e) * 131 + 2];
      }
    }
    #pragma unroll
    for (int c = 0; c < 4; ++c) {
      int p = c * 16 + l15;
      float s0 = 0.f, s1 = 0.f, s2 = 0.f;
      if (LAYER1) { s0 = buf[p * 132 + 128]; s1 = buf[p * 132 + 129]; s2 = buf[p * 132 + 130]; }
      f32x4 yv;
      #pragma unroll
      for (int e = 0; e < 4; ++e) {
        float y = acc[r][c][e] + bb[e];
        if (LAYER1) y += w1c[e][0] * s0 + w1c[e][1] * s1 + w1c[e][2] * s2;
        y = (y >= 0.f) ? y : 0.1f * y;
        yv[e] = y;
        if (LAST) og[(size_t)(ob + e) * HW + p] = y;
      }
      if (!LAST) *(f32x4*)&buf[p * 132 + ob] = yv;
    }
  }
  __syncthreads();
}

// Fused 3-layer 1x1 conv. Block = 256 thr (4 waves), tile = 128 outch x 64 px.
// Gathers feat3d rows + sideband directly (no feat staging pass).
__global__ __launch_bounds__(256) void k_conv(const float* __restrict__ f3t,
                                              const int* __restrict__ nn_idx,
                                              const float* __restrict__ uv,
                                              const float* __restrict__ corr,
                                              const f16* __restrict__ whl,
                                              const float* __restrict__ w1full,
                                              const float* __restrict__ b1,
                                              const float* __restrict__ b2,
                                              const float* __restrict__ b3,
                                              float* __restrict__ out) {
  __shared__ float buf[64 * 132];
  __shared__ int js[64];
  int blk = blockIdx.x;              // 768 = 2 * 384
  int b = blk / 384;
  int q0 = (blk - b * 384) * 64;
  int tid = threadIdx.x;
  int lane = tid & 63, wv = tid >> 6;
  int l15 = lane & 15, l4 = lane >> 4;

  if (tid < 64) js[tid] = nn_idx[b * HW + q0 + tid];
  __syncthreads();
  for (int i = tid; i < 64 * 33; i += 256) {
    int row = i / 33, c = i - row * 33;
    if (c < 32) {
      *(f32x4*)&buf[row * 132 + c * 4] =
          *(const f32x4*)&f3t[((size_t)(b * NPTS + js[row])) * CH + c * 4];
    } else {
      int q = q0 + row;
      int j = js[row];
      float u = uv[b * 2 * NPTS + j], v = uv[b * 2 * NPTS + NPTS + j];
      float xq = (float)(q % WID), yq = (float)(q / WID);
      f32x4 t = {u - xq, v - yq, corr[b * HW + q], 0.f};
      *(f32x4*)&buf[row * 132 + 128] = t;
    }
  }
  __syncthreads();

  float* og = out + (size_t)b * CH * HW + q0;
  conv_layer<true,  false>(buf, whl + 0 * 16384, whl + 1 * 16384, b1, w1full, og, wv, l15, l4);
  conv_layer<false, false>(buf, whl + 2 * 16384, whl + 3 * 16384, b2, nullptr, og, wv, l15, l4);
  conv_layer<false, true >(buf, whl + 4 * 16384, whl + 5 * 16384, b3, nullptr, og, wv, l15, l4);
}

extern "C" void kernel_launch(void* const* d_in, const int* in_sizes, int n_in,
                              void* d_out, int out_size, void* d_ws, size_t ws_size,
                              hipStream_t stream) {
  const float* uv     = (const float*)d_in[0];
  const float* feat2d = (const float*)d_in[1];
  const float* feat3d = (const float*)d_in[2];
  const float* w1 = (const float*)d_in[3];
  const float* b1 = (const float*)d_in[4];
  const float* w2 = (const float*)d_in[5];
  const float* b2 = (const float*)d_in[6];
  const float* w3 = (const float*)d_in[7];
  const float* b3 = (const float*)d_in[8];
  float* out = (float*)d_out;
  char* ws = (char*)d_ws;
  int*   nn_idx  = (int*)(ws + OFF_NNIDX);
  float* corr    = (float*)(ws + OFF_CORR);
  float* sampled = (float*)(ws + OFF_SAMPLED);
  float* f3t     = (float*)(ws + OFF_F3T);
  f16*   whl     = (f16*)(ws + OFF_WHL);

  k_prep_w<<<dim3(192),  dim3(256), 0, stream>>>(w1, w2, w3, whl);
  k_sample<<<dim3(4096), dim3(256), 0, stream>>>(uv, feat2d, feat3d, sampled, f3t);
  k_nn    <<<dim3(768),  dim3(256), 0, stream>>>(uv, nn_idx);
  k_corr  <<<dim3(768),  dim3(256), 0, stream>>>(nn_idx, sampled, feat2d, corr);
  k_conv  <<<dim3(768),  dim3(256), 0, stream>>>(f3t, nn_idx, uv, corr, whl, w1,
                                                 b1, b2, b3, out);
}

// Round 16
// 150.893 us; speedup vs baseline: 1.0727x; 1.0727x over previous
//
#include <hip/hip_runtime.h>

typedef _Float16 f16;
typedef f16  f16x8 __attribute__((ext_vector_type(8)));
typedef float f32x4 __attribute__((ext_vector_type(4)));

#define NPTS 4096
#define HW   24576
#define WID  192
#define CH   128

// ---- workspace layout (bytes) ----
#define OFF_NNIDX   (0u)           // int[49152]
#define OFF_CORR    (196608u)      // float[49152]
#define OFF_SAMPLED (393216u)      // float[8192*128]
#define OFF_F3T     (4587520u)     // float[8192*128]
#define OFF_WHL     (8781824u)     // f16[3][2][128][128]  (layer, hi/lo)
// total 8978432 bytes (~9 MB)

// Split weights into f16 hi/lo pairs: w = wh + wl (+ O(5e-4^2) dropped).
__global__ __launch_bounds__(256) void k_prep_w(const float* __restrict__ w1,
                                                const float* __restrict__ w2,
                                                const float* __restrict__ w3,
                                                f16* __restrict__ whl) {
  int i = blockIdx.x * 256 + threadIdx.x;   // 3*16384
  if (i >= 49152) return;
  int layer = i >> 14;
  int r = i & 16383;
  int o = r >> 7, k = r & 127;
  float v;
  if (layer == 0)      v = w1[o * 131 + 3 + k];
  else if (layer == 1) v = w2[o * 128 + k];
  else                 v = w3[o * 128 + k];
  f16 h = (f16)v;
  f16 l = (f16)(v - (float)h);
  whl[(layer * 2 + 0) * 16384 + r] = h;
  whl[(layer * 2 + 1) * 16384 + r] = l;
}

// Bilinear sample, ONE (b,c) plane per block: all gathers of a wave hit the
// same 96KB plane (L1/L2-hot), uv reads coalesced. 512 thr, 8 pts/thread.
__global__ __launch_bounds__(512) void k_sample(const float* __restrict__ uv,
                                                const float* __restrict__ feat2d,
                                                const float* __restrict__ feat3d,
                                                float* __restrict__ sampled,
                                                float* __restrict__ f3t) {
  int bc = blockIdx.x;               // 256 = 2 batches * 128 channels
  int b = bc >> 7, c = bc & 127;
  const float* up = uv + b * 2 * NPTS;
  const float* fp = feat2d + (size_t)(b * CH + c) * HW;
  const float* f3 = feat3d + (size_t)(b * CH + c) * NPTS;
  for (int p = threadIdx.x; p < NPTS; p += 512) {
    float u = up[p], v = up[NPTS + p];
    float x0f = floorf(u), y0f = floorf(v);
    float wx = u - x0f, wy = v - y0f;
    int x0 = (int)x0f; x0 = min(max(x0, 0), WID - 1);
    int x1 = min(x0 + 1, WID - 1);
    int y0 = (int)y0f; y0 = min(max(y0, 0), 127);
    int y1 = min(y0 + 1, 127);
    float g00 = fp[y0 * WID + x0], g01 = fp[y0 * WID + x1];
    float g10 = fp[y1 * WID + x0], g11 = fp[y1 * WID + x1];
    float s = g00 * (1.f - wx) * (1.f - wy) + g01 * wx * (1.f - wy)
            + g10 * (1.f - wx) * wy + g11 * wx * wy;
    sampled[(size_t)(b * NPTS + p) * CH + c] = s;
    f3t[(size_t)(b * NPTS + p) * CH + c] = f3[p];
  }
}

// Argmin in two passes.
// Pass A: UNPINNED approximate d2a=(x-u)^2+(y-v)^2 min-scan (pipelineable).
// Pass B: rescan; for candidates with d2a <= m+EPS evaluate the bit-exact
// pinned reference formula (qp=fma(y,v,RN(xu)); ssu=RN(RN(u^2)+RN(v^2));
// d2=RN(RN(ssg-RN(2qp))+ssu)); strict-< ascending + ascending quarter merge
// == reference first-index semantics. EPS=0.15 >> max |d2_ref-d2_exact|*2.
__global__ __launch_bounds__(256) void k_nn(const float* __restrict__ uv,
                                            int* __restrict__ nn_idx) {
#pragma clang fp contract(off)
  __shared__ float us[NPTS];
  __shared__ float vs[NPTS];
  __shared__ float ssus[NPTS];
  __shared__ float bd[4][64];
  __shared__ int   bis[4][64];
  int blk = blockIdx.x;              // 768 = 2 batches * 384
  int b = blk / 384;
  int q0 = (blk - b * 384) * 64;
  const float* up = uv + b * 2 * NPTS;
  for (int p = threadIdx.x; p < NPTS; p += 256) {
    float u = up[p], v = up[NPTS + p];
    us[p] = u; vs[p] = v;
    float uu = u * u;   asm volatile("" : "+v"(uu));
    float vv = v * v;   asm volatile("" : "+v"(vv));
    float ss = uu + vv; asm volatile("" : "+v"(ss));
    ssus[p] = ss;
  }
  __syncthreads();
  int px = threadIdx.x & 63;
  int qt = threadIdx.x >> 6;         // point-quarter
  int q = q0 + px;
  float xq = (float)(q % WID);
  float yq = (float)(q / WID);
  float ssg = xq * xq + yq * yq;     // exact (integers < 2^24)
  int pbeg = qt * 1024, pend = pbeg + 1024;

  // ---- Pass A: approximate min (4 independent chains) ----
  float m0 = 3.4e38f, m1 = 3.4e38f, m2 = 3.4e38f, m3 = 3.4e38f;
  for (int p = pbeg; p < pend; p += 4) {
    f32x4 u4 = *(const f32x4*)&us[p];
    f32x4 v4 = *(const f32x4*)&vs[p];
    float dx0 = xq - u4[0], dy0 = yq - v4[0];
    float dx1 = xq - u4[1], dy1 = yq - v4[1];
    float dx2 = xq - u4[2], dy2 = yq - v4[2];
    float dx3 = xq - u4[3], dy3 = yq - v4[3];
    m0 = fminf(m0, fmaf(dy0, dy0, dx0 * dx0));
    m1 = fminf(m1, fmaf(dy1, dy1, dx1 * dx1));
    m2 = fminf(m2, fmaf(dy2, dy2, dx2 * dx2));
    m3 = fminf(m3, fmaf(dy3, dy3, dx3 * dx3));
  }
  bd[qt][px] = fminf(fminf(m0, m1), fminf(m2, m3));
  __syncthreads();
  float mEps = fminf(fminf(bd[0][px], bd[1][px]),
                     fminf(bd[2][px], bd[3][px])) + 0.15f;
  __syncthreads();

  // ---- Pass B: pinned-exact evaluation of candidates ----
  float bestr = 3.4e38f; int bir = 0;
  for (int p = pbeg; p < pend; p += 4) {
    f32x4 u4 = *(const f32x4*)&us[p];
    f32x4 v4 = *(const f32x4*)&vs[p];
    float dx0 = xq - u4[0], dy0 = yq - v4[0];
    float dx1 = xq - u4[1], dy1 = yq - v4[1];
    float dx2 = xq - u4[2], dy2 = yq - v4[2];
    float dx3 = xq - u4[3], dy3 = yq - v4[3];
    float a0 = fmaf(dy0, dy0, dx0 * dx0);
    float a1 = fmaf(dy1, dy1, dx1 * dx1);
    float a2 = fmaf(dy2, dy2, dx2 * dx2);
    float a3 = fmaf(dy3, dy3, dx3 * dx3);
    if ((a0 <= mEps) | (a1 <= mEps) | (a2 <= mEps) | (a3 <= mEps)) {
      #pragma unroll
      for (int i = 0; i < 4; ++i) {
        float ai = (i == 0) ? a0 : (i == 1) ? a1 : (i == 2) ? a2 : a3;
        if (ai <= mEps) {
          float tx = u4[i], ty = v4[i];
          float xu = xq * tx;                       asm volatile("" : "+v"(xu));
          float qp = __builtin_fmaf(yq, ty, xu);    asm volatile("" : "+v"(qp));
          float tq = 2.0f * qp;                     asm volatile("" : "+v"(tq));
          float t1 = ssg - tq;                      asm volatile("" : "+v"(t1));
          float d2 = t1 + ssus[p + i];              asm volatile("" : "+v"(d2));
          if (d2 < bestr) { bestr = d2; bir = p + i; }
        }
      }
    }
  }
  bd[qt][px] = bestr; bis[qt][px] = bir;
  __syncthreads();
  if (qt == 0) {
    float best = bestr; int bi = bir;
    #pragma unroll
    for (int k = 1; k < 4; ++k) {
      float d = bd[k][px];
      if (d < best) { best = d; bi = bis[k][px]; }  // strict < keeps earliest idx
    }
    nn_idx[b * HW + q] = bi;
  }
}

// corr[q] = mean_c sampled[j][c] * feat2d[c][q]   (f32)
__global__ __launch_bounds__(256) void k_corr(const int* __restrict__ nn_idx,
                                              const float* __restrict__ sampled,
                                              const float* __restrict__ feat2d,
                                              float* __restrict__ corr) {
  __shared__ float part[4][64];
  int blk = blockIdx.x;
  int b = blk / 384;
  int q0 = (blk - b * 384) * 64;
  int px = threadIdx.x & 63;
  int cg = threadIdx.x >> 6;
  int q = q0 + px;
  int j = nn_idx[b * HW + q];
  const float* sp = sampled + (size_t)(b * NPTS + j) * CH + cg * 32;
  const float* f2 = feat2d + (size_t)(b * CH + cg * 32) * HW + q;
  float acc = 0.f;
  #pragma unroll 8
  for (int i = 0; i < 32; ++i) acc += sp[i] * f2[(size_t)i * HW];
  part[cg][px] = acc;
  __syncthreads();
  if (cg == 0) {
    float s = (part[0][px] + part[1][px]) + (part[2][px] + part[3][px]);
    corr[b * HW + q] = s * 0.0078125f;
  }
}

// One conv layer via split-f16 MFMA: acc += Wh*xh + Wh*xl + Wl*xh, f32 accum.
// buf: f32 [64 px][132]; in-place (write y over k<128 after barrier).
template<bool LAYER1, bool LAST>
__device__ __forceinline__ void conv_layer(float* buf, const f16* wh, const f16* wl,
                                           const float* bias, const float* w1full,
                                           float* og, int wv, int l15, int l4) {
  f32x4 acc[2][4];
  #pragma unroll
  for (int r = 0; r < 2; ++r)
    #pragma unroll
    for (int c = 0; c < 4; ++c) acc[r][c] = (f32x4){0.f, 0.f, 0.f, 0.f};

  for (int k0 = 0; k0 < 128; k0 += 32) {
    f16x8 ah0 = *(const f16x8*)&wh[(wv * 32 + l15) * 128 + k0 + l4 * 8];
    f16x8 ah1 = *(const f16x8*)&wh[(wv * 32 + 16 + l15) * 128 + k0 + l4 * 8];
    f16x8 al0 = *(const f16x8*)&wl[(wv * 32 + l15) * 128 + k0 + l4 * 8];
    f16x8 al1 = *(const f16x8*)&wl[(wv * 32 + 16 + l15) * 128 + k0 + l4 * 8];
    #pragma unroll
    for (int c = 0; c < 4; ++c) {
      const float* bp = &buf[(c * 16 + l15) * 132 + k0 + l4 * 8];
      f32x4 v0 = *(const f32x4*)bp;
      f32x4 v1 = *(const f32x4*)(bp + 4);
      f16x8 bh, bl;
      #pragma unroll
      for (int i = 0; i < 4; ++i) {
        float x = v0[i]; f16 h = (f16)x; bh[i] = h; bl[i] = (f16)(x - (float)h);
        float x2 = v1[i]; f16 h2 = (f16)x2; bh[4 + i] = h2; bl[4 + i] = (f16)(x2 - (float)h2);
      }
      acc[0][c] = __builtin_amdgcn_mfma_f32_16x16x32_f16(ah0, bh, acc[0][c], 0, 0, 0);
      acc[0][c] = __builtin_amdgcn_mfma_f32_16x16x32_f16(ah0, bl, acc[0][c], 0, 0, 0);
      acc[0][c] = __builtin_amdgcn_mfma_f32_16x16x32_f16(al0, bh, acc[0][c], 0, 0, 0);
      acc[1][c] = __builtin_amdgcn_mfma_f32_16x16x32_f16(ah1, bh, acc[1][c], 0, 0, 0);
      acc[1][c] = __builtin_amdgcn_mfma_f32_16x16x32_f16(ah1, bl, acc[1][c], 0, 0, 0);
      acc[1][c] = __builtin_amdgcn_mfma_f32_16x16x32_f16(al1, bh, acc[1][c], 0, 0, 0);
    }
  }
  __syncthreads();   // all reads of buf done before in-place overwrite
  #pragma unroll
  for (int r = 0; r < 2; ++r) {
    int ob = wv * 32 + r * 16 + l4 * 4;
    f32x4 bb = *(const f32x4*)&bias[ob];
    float w1c[4][3];
    if (LAYER1) {
      #pragma unroll
      for (int e = 0; e < 4; ++e) {
        w1c[e][0] = w1full[(ob + e) * 131 + 0];
        w1c[e][1] = w1full[(ob + e) * 131 + 1];
        w1c[e][2] = w1full[(ob + e) * 131 + 2];
      }
    }
    #pragma unroll
    for (int c = 0; c < 4; ++c) {
      int p = c * 16 + l15;
      float s0 = 0.f, s1 = 0.f, s2 = 0.f;
      if (LAYER1) { s0 = buf[p * 132 + 128]; s1 = buf[p * 132 + 129]; s2 = buf[p * 132 + 130]; }
      f32x4 yv;
      #pragma unroll
      for (int e = 0; e < 4; ++e) {
        float y = acc[r][c][e] + bb[e];
        if (LAYER1) y += w1c[e][0] * s0 + w1c[e][1] * s1 + w1c[e][2] * s2;
        y = (y >= 0.f) ? y : 0.1f * y;
        yv[e] = y;
        if (LAST) og[(size_t)(ob + e) * HW + p] = y;
      }
      if (!LAST) *(f32x4*)&buf[p * 132 + ob] = yv;
    }
  }
  __syncthreads();
}

// Fused 3-layer 1x1 conv. Block = 256 thr (4 waves), tile = 128 outch x 64 px.
__global__ __launch_bounds__(256) void k_conv(const float* __restrict__ f3t,
                                              const int* __restrict__ nn_idx,
                                              const float* __restrict__ uv,
                                              const float* __restrict__ corr,
                                              const f16* __restrict__ whl,
                                              const float* __restrict__ w1full,
                                              const float* __restrict__ b1,
                                              const float* __restrict__ b2,
                                              const float* __restrict__ b3,
                                              float* __restrict__ out) {
  __shared__ float buf[64 * 132];
  __shared__ int js[64];
  int blk = blockIdx.x;              // 768 = 2 * 384
  int b = blk / 384;
  int q0 = (blk - b * 384) * 64;
  int tid = threadIdx.x;
  int lane = tid & 63, wv = tid >> 6;
  int l15 = lane & 15, l4 = lane >> 4;

  if (tid < 64) js[tid] = nn_idx[b * HW + q0 + tid];
  __syncthreads();
  for (int i = tid; i < 64 * 33; i += 256) {
    int row = i / 33, c = i - row * 33;
    if (c < 32) {
      *(f32x4*)&buf[row * 132 + c * 4] =
          *(const f32x4*)&f3t[((size_t)(b * NPTS + js[row])) * CH + c * 4];
    } else {
      int q = q0 + row;
      int j = js[row];
      float u = uv[b * 2 * NPTS + j], v = uv[b * 2 * NPTS + NPTS + j];
      float xq = (float)(q % WID), yq = (float)(q / WID);
      f32x4 t = {u - xq, v - yq, corr[b * HW + q], 0.f};
      *(f32x4*)&buf[row * 132 + 128] = t;
    }
  }
  __syncthreads();

  float* og = out + (size_t)b * CH * HW + q0;
  conv_layer<true,  false>(buf, whl + 0 * 16384, whl + 1 * 16384, b1, w1full, og, wv, l15, l4);
  conv_layer<false, false>(buf, whl + 2 * 16384, whl + 3 * 16384, b2, nullptr, og, wv, l15, l4);
  conv_layer<false, true >(buf, whl + 4 * 16384, whl + 5 * 16384, b3, nullptr, og, wv, l15, l4);
}

extern "C" void kernel_launch(void* const* d_in, const int* in_sizes, int n_in,
                              void* d_out, int out_size, void* d_ws, size_t ws_size,
                              hipStream_t stream) {
  const float* uv     = (const float*)d_in[0];
  const float* feat2d = (const float*)d_in[1];
  const float* feat3d = (const float*)d_in[2];
  const float* w1 = (const float*)d_in[3];
  const float* b1 = (const float*)d_in[4];
  const float* w2 = (const float*)d_in[5];
  const float* b2 = (const float*)d_in[6];
  const float* w3 = (const float*)d_in[7];
  const float* b3 = (const float*)d_in[8];
  float* out = (float*)d_out;
  char* ws = (char*)d_ws;
  int*   nn_idx  = (int*)(ws + OFF_NNIDX);
  float* corr    = (float*)(ws + OFF_CORR);
  float* sampled = (float*)(ws + OFF_SAMPLED);
  float* f3t     = (float*)(ws + OFF_F3T);
  f16*   whl     = (f16*)(ws + OFF_WHL);

  k_prep_w<<<dim3(192),  dim3(256), 0, stream>>>(w1, w2, w3, whl);
  k_sample<<<dim3(256),  dim3(512), 0, stream>>>(uv, feat2d, feat3d, sampled, f3t);
  k_nn    <<<dim3(768),  dim3(256), 0, stream>>>(uv, nn_idx);
  k_corr  <<<dim3(768),  dim3(256), 0, stream>>>(nn_idx, sampled, feat2d, corr);
  k_conv  <<<dim3(768),  dim3(256), 0, stream>>>(f3t, nn_idx, uv, corr, whl, w1,
                                                 b1, b2, b3, out);
}

// Round 18
// 114.628 us; speedup vs baseline: 1.4121x; 1.3164x over previous
//
#include <hip/hip_runtime.h>

typedef _Float16 f16;
typedef f16  f16x8 __attribute__((ext_vector_type(8)));
typedef float f32x4 __attribute__((ext_vector_type(4)));

#define NPTS 4096
#define HW   24576
#define WID  192
#define CH   128
#define NCX  24
#define NCY  16
#define NCELL 384
#define EPS  0.15f

// ---- workspace layout (bytes) ----  (total 8978432, same as passing R16)
#define OFF_NNIDX   (0u)           // int[49152]
#define OFF_CORR    (196608u)      // float[49152]  -- ALSO holds pts/offs early
#define OFF_SAMPLED (393216u)      // float[8192*128]
#define OFF_F3T     (4587520u)     // float[8192*128]
#define OFF_WHL     (8781824u)     // f16[3][2][128][128]
// pts/offs live inside the CORR region: pts dead before k_corr writes corr.
#define OFF_PTS     (OFF_CORR)             // float4[2][4096] = 131072 B
#define OFF_OFFS    (OFF_CORR + 131072u)   // int[2][385]     = 3080 B  (<196608)

__device__ __forceinline__ int cell_of(float u, float v) {
  int cx = (int)(u * 0.125f); cx = min(max(cx, 0), NCX - 1);
  int cy = (int)(v * 0.125f); cy = min(max(cy, 0), NCY - 1);
  return cy * NCX + cx;
}

// Split weights into f16 hi/lo pairs: w = wh + wl.
__global__ __launch_bounds__(256) void k_prep_w(const float* __restrict__ w1,
                                                const float* __restrict__ w2,
                                                const float* __restrict__ w3,
                                                f16* __restrict__ whl) {
  int i = blockIdx.x * 256 + threadIdx.x;   // 3*16384
  if (i >= 49152) return;
  int layer = i >> 14;
  int r = i & 16383;
  int o = r >> 7, k = r & 127;
  float v;
  if (layer == 0)      v = w1[o * 131 + 3 + k];
  else if (layer == 1) v = w2[o * 128 + k];
  else                 v = w3[o * 128 + k];
  f16 h = (f16)v;
  f16 l = (f16)(v - (float)h);
  whl[(layer * 2 + 0) * 16384 + r] = h;
  whl[(layer * 2 + 1) * 16384 + r] = l;
}

// Bilinear sample, ONE (b,c) plane per block (L1/L2-hot gathers).
__global__ __launch_bounds__(512) void k_sample(const float* __restrict__ uv,
                                                const float* __restrict__ feat2d,
                                                const float* __restrict__ feat3d,
                                                float* __restrict__ sampled,
                                                float* __restrict__ f3t) {
  int bc = blockIdx.x;               // 256 = 2 * 128
  int b = bc >> 7, c = bc & 127;
  const float* up = uv + b * 2 * NPTS;
  const float* fp = feat2d + (size_t)(b * CH + c) * HW;
  const float* f3 = feat3d + (size_t)(b * CH + c) * NPTS;
  for (int p = threadIdx.x; p < NPTS; p += 512) {
    float u = up[p], v = up[NPTS + p];
    float x0f = floorf(u), y0f = floorf(v);
    float wx = u - x0f, wy = v - y0f;
    int x0 = (int)x0f; x0 = min(max(x0, 0), WID - 1);
    int x1 = min(x0 + 1, WID - 1);
    int y0 = (int)y0f; y0 = min(max(y0, 0), 127);
    int y1 = min(y0 + 1, 127);
    float g00 = fp[y0 * WID + x0], g01 = fp[y0 * WID + x1];
    float g10 = fp[y1 * WID + x0], g11 = fp[y1 * WID + x1];
    float s = g00 * (1.f - wx) * (1.f - wy) + g01 * wx * (1.f - wy)
            + g10 * (1.f - wx) * wy + g11 * wx * wy;
    sampled[(size_t)(b * NPTS + p) * CH + c] = s;
    f3t[(size_t)(b * NPTS + p) * CH + c] = f3[p];
  }
}

// Bin points into 24x16 cells; store sorted float4{u, v, ssu_pinned, idx}.
// ssu = RN(RN(u*u)+RN(v*v)) pinned -- same rounding as the verified k_nn.
__global__ __launch_bounds__(512) void k_bin(const float* __restrict__ uv,
                                             float4* __restrict__ pts,
                                             int* __restrict__ offs) {
#pragma clang fp contract(off)
  __shared__ int cnt[NCELL];
  __shared__ int base[NCELL + 1];
  int b = blockIdx.x;
  int tid = threadIdx.x;
  const float* up = uv + b * 2 * NPTS;
  for (int i = tid; i < NCELL; i += 512) cnt[i] = 0;
  __syncthreads();
  for (int p = tid; p < NPTS; p += 512)
    atomicAdd(&cnt[cell_of(up[p], up[NPTS + p])], 1);
  __syncthreads();
  if (tid == 0) {
    int s = 0;
    for (int i = 0; i < NCELL; ++i) { base[i] = s; s += cnt[i]; }
    base[NCELL] = s;
  }
  __syncthreads();
  for (int i = tid; i <= NCELL; i += 512) offs[b * (NCELL + 1) + i] = base[i];
  for (int i = tid; i < NCELL; i += 512) cnt[i] = base[i];
  __syncthreads();
  for (int p = tid; p < NPTS; p += 512) {
    float u = up[p], v = up[NPTS + p];
    int pos = atomicAdd(&cnt[cell_of(u, v)], 1);
    float uu = u * u;   asm volatile("" : "+v"(uu));
    float vv = v * v;   asm volatile("" : "+v"(vv));
    float ss = uu + vv; asm volatile("" : "+v"(ss));
    float4 t; t.x = u; t.y = v; t.z = ss; t.w = __int_as_float(p);
    pts[b * NPTS + pos] = t;
  }
}

// NN query: one WAVE per 8x8 pixel tile (= one cell). Ring scan of cells;
// per candidate (d2a <= m+EPS) evaluate the bit-exact pinned reference d2
// (qp=fma(y,v,RN(xu)); d2=RN(RN(ssg-RN(2qp))+ssu)); lexicographic (d2,idx)
// min == reference first-index strict-< semantics (scan-order independent).
__global__ __launch_bounds__(128) void k_nnq(const float4* __restrict__ pts,
                                             const int* __restrict__ offs,
                                             int* __restrict__ nn_idx) {
#pragma clang fp contract(off)
  int tile = blockIdx.x * 2 + (threadIdx.x >> 6);   // 768 tiles
  int lane = threadIdx.x & 63;
  int b = tile / NCELL;
  int t = tile - b * NCELL;
  int ty = t / NCX, tx = t - ty * NCX;
  int px = tx * 8 + (lane & 7);
  int py = ty * 8 + (lane >> 3);
  float xq = (float)px, yq = (float)py;
  float ssg = xq * xq + yq * yq;     // exact (ints < 2^24)
  const float4* P = pts + b * NPTS;
  const int* O = offs + b * (NCELL + 1);

  float m = 3.4e38f;
  float bestr = 3.4e38f; int bir = 0x7fffffff;

  for (int R = 0; R < 24; ++R) {
    if (R > 0) {
      float mm = m;
      #pragma unroll
      for (int o = 32; o; o >>= 1) mm = fmaxf(mm, __shfl_xor(mm, o));
      float bound = 64.f * (float)((R - 1) * (R - 1));
      if (bound > mm + EPS) break;
    }
    int x0 = max(0, tx - R), x1 = min(NCX - 1, tx + R);
    int y0 = max(0, ty - R), y1 = min(NCY - 1, ty + R);
    for (int cy = y0; cy <= y1; ++cy) {
      for (int cx = x0; cx <= x1; ++cx) {
        int cd = max(abs(cx - tx), abs(cy - ty));
        if (cd != R) continue;
        int c = cy * NCX + cx;
        int s = O[c], e = O[c + 1];
        for (int i = s; i < e; ++i) {
          float4 pt = P[i];
          float dx = xq - pt.x, dy = yq - pt.y;
          float d2a = fmaf(dy, dy, dx * dx);
          m = fminf(m, d2a);
          if (d2a <= m + EPS) {
            float xu = xq * pt.x;                       asm volatile("" : "+v"(xu));
            float qp = __builtin_fmaf(yq, pt.y, xu);    asm volatile("" : "+v"(qp));
            float tq = 2.0f * qp;                       asm volatile("" : "+v"(tq));
            float t1 = ssg - tq;                        asm volatile("" : "+v"(t1));
            float d2 = t1 + pt.z;                       asm volatile("" : "+v"(d2));
            int pi = __float_as_int(pt.w);
            if (d2 < bestr || (d2 == bestr && pi < bir)) { bestr = d2; bir = pi; }
          }
        }
      }
    }
  }
  nn_idx[b * HW + py * WID + px] = bir;
}

// corr[q] = mean_c sampled[j][c] * feat2d[c][q]   (f32)
__global__ __launch_bounds__(256) void k_corr(const int* __restrict__ nn_idx,
                                              const float* __restrict__ sampled,
                                              const float* __restrict__ feat2d,
                                              float* __restrict__ corr) {
  __shared__ float part[4][64];
  int blk = blockIdx.x;
  int b = blk / 384;
  int q0 = (blk - b * 384) * 64;
  int px = threadIdx.x & 63;
  int cg = threadIdx.x >> 6;
  int q = q0 + px;
  int j = nn_idx[b * HW + q];
  const float* sp = sampled + (size_t)(b * NPTS + j) * CH + cg * 32;
  const float* f2 = feat2d + (size_t)(b * CH + cg * 32) * HW + q;
  float acc = 0.f;
  #pragma unroll 8
  for (int i = 0; i < 32; ++i) acc += sp[i] * f2[(size_t)i * HW];
  part[cg][px] = acc;
  __syncthreads();
  if (cg == 0) {
    float s = (part[0][px] + part[1][px]) + (part[2][px] + part[3][px]);
    corr[b * HW + q] = s * 0.0078125f;
  }
}

// One conv layer via split-f16 MFMA: acc += Wh*xh + Wh*xl + Wl*xh, f32 accum.
template<bool LAYER1, bool LAST>
__device__ __forceinline__ void conv_layer(float* buf, const f16* wh, const f16* wl,
                                           const float* bias, const float* w1full,
                                           float* og, int wv, int l15, int l4) {
  f32x4 acc[2][4];
  #pragma unroll
  for (int r = 0; r < 2; ++r)
    #pragma unroll
    for (int c = 0; c < 4; ++c) acc[r][c] = (f32x4){0.f, 0.f, 0.f, 0.f};

  for (int k0 = 0; k0 < 128; k0 += 32) {
    f16x8 ah0 = *(const f16x8*)&wh[(wv * 32 + l15) * 128 + k0 + l4 * 8];
    f16x8 ah1 = *(const f16x8*)&wh[(wv * 32 + 16 + l15) * 128 + k0 + l4 * 8];
    f16x8 al0 = *(const f16x8*)&wl[(wv * 32 + l15) * 128 + k0 + l4 * 8];
    f16x8 al1 = *(const f16x8*)&wl[(wv * 32 + 16 + l15) * 128 + k0 + l4 * 8];
    #pragma unroll
    for (int c = 0; c < 4; ++c) {
      const float* bp = &buf[(c * 16 + l15) * 132 + k0 + l4 * 8];
      f32x4 v0 = *(const f32x4*)bp;
      f32x4 v1 = *(const f32x4*)(bp + 4);
      f16x8 bh, bl;
      #pragma unroll
      for (int i = 0; i < 4; ++i) {
        float x = v0[i]; f16 h = (f16)x; bh[i] = h; bl[i] = (f16)(x - (float)h);
        float x2 = v1[i]; f16 h2 = (f16)x2; bh[4 + i] = h2; bl[4 + i] = (f16)(x2 - (float)h2);
      }
      acc[0][c] = __builtin_amdgcn_mfma_f32_16x16x32_f16(ah0, bh, acc[0][c], 0, 0, 0);
      acc[0][c] = __builtin_amdgcn_mfma_f32_16x16x32_f16(ah0, bl, acc[0][c], 0, 0, 0);
      acc[0][c] = __builtin_amdgcn_mfma_f32_16x16x32_f16(al0, bh, acc[0][c], 0, 0, 0);
      acc[1][c] = __builtin_amdgcn_mfma_f32_16x16x32_f16(ah1, bh, acc[1][c], 0, 0, 0);
      acc[1][c] = __builtin_amdgcn_mfma_f32_16x16x32_f16(ah1, bl, acc[1][c], 0, 0, 0);
      acc[1][c] = __builtin_amdgcn_mfma_f32_16x16x32_f16(al1, bh, acc[1][c], 0, 0, 0);
    }
  }
  __syncthreads();
  #pragma unroll
  for (int r = 0; r < 2; ++r) {
    int ob = wv * 32 + r * 16 + l4 * 4;
    f32x4 bb = *(const f32x4*)&bias[ob];
    float w1c[4][3];
    if (LAYER1) {
      #pragma unroll
      for (int e = 0; e < 4; ++e) {
        w1c[e][0] = w1full[(ob + e) * 131 + 0];
        w1c[e][1] = w1full[(ob + e) * 131 + 1];
        w1c[e][2] = w1full[(ob + e) * 131 + 2];
      }
    }
    #pragma unroll
    for (int c = 0; c < 4; ++c) {
      int p = c * 16 + l15;
      float s0 = 0.f, s1 = 0.f, s2 = 0.f;
      if (LAYER1) { s0 = buf[p * 132 + 128]; s1 = buf[p * 132 + 129]; s2 = buf[p * 132 + 130]; }
      f32x4 yv;
      #pragma unroll
      for (int e = 0; e < 4; ++e) {
        float y = acc[r][c][e] + bb[e];
        if (LAYER1) y += w1c[e][0] * s0 + w1c[e][1] * s1 + w1c[e][2] * s2;
        y = (y >= 0.f) ? y : 0.1f * y;
        yv[e] = y;
        if (LAST) og[(size_t)(ob + e) * HW + p] = y;
      }
      if (!LAST) *(f32x4*)&buf[p * 132 + ob] = yv;
    }
  }
  __syncthreads();
}

// Fused 3-layer 1x1 conv. Block = 256 thr, tile = 128 outch x 64 px.
__global__ __launch_bounds__(256) void k_conv(const float* __restrict__ f3t,
                                              const int* __restrict__ nn_idx,
                                              const float* __restrict__ uv,
                                              const float* __restrict__ corr,
                                              const f16* __restrict__ whl,
                                              const float* __restrict__ w1full,
                                              const float* __restrict__ b1,
                                              const float* __restrict__ b2,
                                              const float* __restrict__ b3,
                                              float* __restrict__ out) {
  __shared__ float buf[64 * 132];
  __shared__ int js[64];
  int blk = blockIdx.x;              // 768 = 2 * 384
  int b = blk / 384;
  int q0 = (blk - b * 384) * 64;
  int tid = threadIdx.x;
  int lane = tid & 63, wv = tid >> 6;
  int l15 = lane & 15, l4 = lane >> 4;

  if (tid < 64) js[tid] = nn_idx[b * HW + q0 + tid];
  __syncthreads();
  for (int i = tid; i < 64 * 33; i += 256) {
    int row = i / 33, c = i - row * 33;
    if (c < 32) {
      *(f32x4*)&buf[row * 132 + c * 4] =
          *(const f32x4*)&f3t[((size_t)(b * NPTS + js[row])) * CH + c * 4];
    } else {
      int q = q0 + row;
      int j = js[row];
      float u = uv[b * 2 * NPTS + j], v = uv[b * 2 * NPTS + NPTS + j];
      float xq = (float)(q % WID), yq = (float)(q / WID);
      f32x4 t = {u - xq, v - yq, corr[b * HW + q], 0.f};
      *(f32x4*)&buf[row * 132 + 128] = t;
    }
  }
  __syncthreads();

  float* og = out + (size_t)b * CH * HW + q0;
  conv_layer<true,  false>(buf, whl + 0 * 16384, whl + 1 * 16384, b1, w1full, og, wv, l15, l4);
  conv_layer<false, false>(buf, whl + 2 * 16384, whl + 3 * 16384, b2, nullptr, og, wv, l15, l4);
  conv_layer<false, true >(buf, whl + 4 * 16384, whl + 5 * 16384, b3, nullptr, og, wv, l15, l4);
}

extern "C" void kernel_launch(void* const* d_in, const int* in_sizes, int n_in,
                              void* d_out, int out_size, void* d_ws, size_t ws_size,
                              hipStream_t stream) {
  const float* uv     = (const float*)d_in[0];
  const float* feat2d = (const float*)d_in[1];
  const float* feat3d = (const float*)d_in[2];
  const float* w1 = (const float*)d_in[3];
  const float* b1 = (const float*)d_in[4];
  const float* w2 = (const float*)d_in[5];
  const float* b2 = (const float*)d_in[6];
  const float* w3 = (const float*)d_in[7];
  const float* b3 = (const float*)d_in[8];
  float* out = (float*)d_out;
  char* ws = (char*)d_ws;
  int*    nn_idx  = (int*)(ws + OFF_NNIDX);
  float*  corr    = (float*)(ws + OFF_CORR);
  float*  sampled = (float*)(ws + OFF_SAMPLED);
  float*  f3t     = (float*)(ws + OFF_F3T);
  f16*    whl     = (f16*)(ws + OFF_WHL);
  float4* pts     = (float4*)(ws + OFF_PTS);   // aliases corr region (dead
  int*    offs    = (int*)(ws + OFF_OFFS);     // before k_corr writes corr)

  k_prep_w<<<dim3(192), dim3(256), 0, stream>>>(w1, w2, w3, whl);
  k_bin   <<<dim3(2),   dim3(512), 0, stream>>>(uv, pts, offs);
  k_sample<<<dim3(256), dim3(512), 0, stream>>>(uv, feat2d, feat3d, sampled, f3t);
  k_nnq   <<<dim3(384), dim3(128), 0, stream>>>(pts, offs, nn_idx);
  k_corr  <<<dim3(768), dim3(256), 0, stream>>>(nn_idx, sampled, feat2d, corr);
  k_conv  <<<dim3(768), dim3(256), 0, stream>>>(f3t, nn_idx, uv, corr, whl, w1,
                                                b1, b2, b3, out);
}

// Round 19
// 104.643 us; speedup vs baseline: 1.5469x; 1.0954x over previous
//
#include <hip/hip_runtime.h>

typedef _Float16 f16;
typedef f16  f16x8 __attribute__((ext_vector_type(8)));
typedef float f32x4 __attribute__((ext_vector_type(4)));

#define NPTS 4096
#define HW   24576
#define WID  192
#define CH   128
#define NCX  24
#define NCY  16
#define NCELL 384
#define EPS  0.15f

// ---- workspace layout (bytes) ----  (total 8978432, same as passing R16/R18)
#define OFF_NNIDX   (0u)           // int[49152]
#define OFF_CORR    (196608u)      // float[49152]  -- ALSO holds pts/offs early
#define OFF_SAMPLED (393216u)      // (unused now)
#define OFF_F3T     (4587520u)     // float[8192*128]
#define OFF_WHL     (8781824u)     // f16[3][2][128][128]
#define OFF_PTS     (OFF_CORR)             // float4[2][4096] = 131072 B
#define OFF_OFFS    (OFF_CORR + 131072u)   // int[2][385]     = 3080 B

__device__ __forceinline__ int cell_of(float u, float v) {
  int cx = (int)(u * 0.125f); cx = min(max(cx, 0), NCX - 1);
  int cy = (int)(v * 0.125f); cy = min(max(cy, 0), NCY - 1);
  return cy * NCX + cx;
}

// Split weights into f16 hi/lo pairs: w = wh + wl.
__global__ __launch_bounds__(256) void k_prep_w(const float* __restrict__ w1,
                                                const float* __restrict__ w2,
                                                const float* __restrict__ w3,
                                                f16* __restrict__ whl) {
  int i = blockIdx.x * 256 + threadIdx.x;   // 3*16384
  if (i >= 49152) return;
  int layer = i >> 14;
  int r = i & 16383;
  int o = r >> 7, k = r & 127;
  float v;
  if (layer == 0)      v = w1[o * 131 + 3 + k];
  else if (layer == 1) v = w2[o * 128 + k];
  else                 v = w3[o * 128 + k];
  f16 h = (f16)v;
  f16 l = (f16)(v - (float)h);
  whl[(layer * 2 + 0) * 16384 + r] = h;
  whl[(layer * 2 + 1) * 16384 + r] = l;
}

// LDS-tiled transpose: feat3d[b][c][p] -> f3t[b][p][c]. Tile 32c x 64p.
__global__ __launch_bounds__(256) void k_tr(const float* __restrict__ feat3d,
                                            float* __restrict__ f3t) {
  __shared__ float tile[32][65];
  int blk = blockIdx.x;              // 2 * 4 * 64 = 512
  int b = blk >> 8;
  int r = blk & 255;
  int cg = r >> 6;                   // 0..3  (32-channel group)
  int pg = r & 63;                   // 0..63 (64-point group)
  int c0 = cg * 32, p0 = pg * 64;
  int tid = threadIdx.x;
  { // read: 32 rows x 64 cols, coalesced over p
    int p = tid & 63;
    int c = tid >> 6;                // 0..3, step 4
    #pragma unroll
    for (int cc = 0; cc < 32; cc += 4)
      tile[c + cc][p] = feat3d[(size_t)(b * CH + c0 + c + cc) * NPTS + p0 + p];
  }
  __syncthreads();
  { // write: 64 rows x 32 cols, coalesced over c
    int c = tid & 31;
    int p = tid >> 5;                // 0..7, step 8
    #pragma unroll
    for (int pp = 0; pp < 64; pp += 8)
      f3t[(size_t)(b * NPTS + p0 + p + pp) * CH + c0 + c] = tile[c][p + pp];
  }
}

// Bin points into 24x16 cells; store sorted float4{u, v, ssu_pinned, idx}.
__global__ __launch_bounds__(512) void k_bin(const float* __restrict__ uv,
                                             float4* __restrict__ pts,
                                             int* __restrict__ offs) {
#pragma clang fp contract(off)
  __shared__ int cnt[NCELL];
  __shared__ int base[NCELL + 1];
  int b = blockIdx.x;
  int tid = threadIdx.x;
  const float* up = uv + b * 2 * NPTS;
  for (int i = tid; i < NCELL; i += 512) cnt[i] = 0;
  __syncthreads();
  for (int p = tid; p < NPTS; p += 512)
    atomicAdd(&cnt[cell_of(up[p], up[NPTS + p])], 1);
  __syncthreads();
  if (tid == 0) {
    int s = 0;
    for (int i = 0; i < NCELL; ++i) { base[i] = s; s += cnt[i]; }
    base[NCELL] = s;
  }
  __syncthreads();
  for (int i = tid; i <= NCELL; i += 512) offs[b * (NCELL + 1) + i] = base[i];
  for (int i = tid; i < NCELL; i += 512) cnt[i] = base[i];
  __syncthreads();
  for (int p = tid; p < NPTS; p += 512) {
    float u = up[p], v = up[NPTS + p];
    int pos = atomicAdd(&cnt[cell_of(u, v)], 1);
    float uu = u * u;   asm volatile("" : "+v"(uu));
    float vv = v * v;   asm volatile("" : "+v"(vv));
    float ss = uu + vv; asm volatile("" : "+v"(ss));
    float4 t; t.x = u; t.y = v; t.z = ss; t.w = __int_as_float(p);
    pts[b * NPTS + pos] = t;
  }
}

// NN query: one WAVE per 8x8 pixel tile. Ring scan; bit-exact pinned ref d2
// for candidates; lexicographic (d2,idx) min == first-index strict-<.
__global__ __launch_bounds__(128) void k_nnq(const float4* __restrict__ pts,
                                             const int* __restrict__ offs,
                                             int* __restrict__ nn_idx) {
#pragma clang fp contract(off)
  int tile = blockIdx.x * 2 + (threadIdx.x >> 6);   // 768 tiles
  int lane = threadIdx.x & 63;
  int b = tile / NCELL;
  int t = tile - b * NCELL;
  int ty = t / NCX, tx = t - ty * NCX;
  int px = tx * 8 + (lane & 7);
  int py = ty * 8 + (lane >> 3);
  float xq = (float)px, yq = (float)py;
  float ssg = xq * xq + yq * yq;
  const float4* P = pts + b * NPTS;
  const int* O = offs + b * (NCELL + 1);

  float m = 3.4e38f;
  float bestr = 3.4e38f; int bir = 0x7fffffff;

  for (int R = 0; R < 24; ++R) {
    if (R > 0) {
      float mm = m;
      #pragma unroll
      for (int o = 32; o; o >>= 1) mm = fmaxf(mm, __shfl_xor(mm, o));
      float bound = 64.f * (float)((R - 1) * (R - 1));
      if (bound > mm + EPS) break;
    }
    int x0 = max(0, tx - R), x1 = min(NCX - 1, tx + R);
    int y0 = max(0, ty - R), y1 = min(NCY - 1, ty + R);
    for (int cy = y0; cy <= y1; ++cy) {
      for (int cx = x0; cx <= x1; ++cx) {
        int cd = max(abs(cx - tx), abs(cy - ty));
        if (cd != R) continue;
        int c = cy * NCX + cx;
        int s = O[c], e = O[c + 1];
        for (int i = s; i < e; ++i) {
          float4 pt = P[i];
          float dx = xq - pt.x, dy = yq - pt.y;
          float d2a = fmaf(dy, dy, dx * dx);
          m = fminf(m, d2a);
          if (d2a <= m + EPS) {
            float xu = xq * pt.x;                       asm volatile("" : "+v"(xu));
            float qp = __builtin_fmaf(yq, pt.y, xu);    asm volatile("" : "+v"(qp));
            float tq = 2.0f * qp;                       asm volatile("" : "+v"(tq));
            float t1 = ssg - tq;                        asm volatile("" : "+v"(t1));
            float d2 = t1 + pt.z;                       asm volatile("" : "+v"(d2));
            int pi = __float_as_int(pt.w);
            if (d2 < bestr || (d2 == bestr && pi < bir)) { bestr = d2; bir = pi; }
          }
        }
      }
    }
  }
  nn_idx[b * HW + py * WID + px] = bir;
}

// Fused corr: per pixel q, bilinear-sample feat_2d at its NN point inline and
// dot with feat2d[:,q].  corr[q] = mean_c bilin(feat2d[c], uv[j]) * f2[c][q].
// Same bilinear formula + ascending-c accumulation + pairwise cgroup combine
// as the verified split version (value changes are ulp-level only).
__global__ __launch_bounds__(256) void k_corr(const int* __restrict__ nn_idx,
                                              const float* __restrict__ uv,
                                              const float* __restrict__ feat2d,
                                              float* __restrict__ corr) {
  __shared__ float part[4][64];
  int blk = blockIdx.x;
  int b = blk / 384;
  int q0 = (blk - b * 384) * 64;
  int px = threadIdx.x & 63;
  int cg = threadIdx.x >> 6;
  int q = q0 + px;
  int j = nn_idx[b * HW + q];
  float u = uv[b * 2 * NPTS + j], v = uv[b * 2 * NPTS + NPTS + j];
  float x0f = floorf(u), y0f = floorf(v);
  float wx = u - x0f, wy = v - y0f;
  int x0 = (int)x0f; x0 = min(max(x0, 0), WID - 1);
  int x1 = min(x0 + 1, WID - 1);
  int y0 = (int)y0f; y0 = min(max(y0, 0), 127);
  int y1 = min(y0 + 1, 127);
  int t00 = y0 * WID + x0, t01 = y0 * WID + x1;
  int t10 = y1 * WID + x0, t11 = y1 * WID + x1;
  float w00 = (1.f - wx) * (1.f - wy), w01 = wx * (1.f - wy);
  float w10 = (1.f - wx) * wy,         w11 = wx * wy;
  const float* fpb = feat2d + (size_t)(b * CH + cg * 32) * HW;
  float acc = 0.f;
  #pragma unroll 8
  for (int i = 0; i < 32; ++i) {
    const float* fp = fpb + (size_t)i * HW;
    float s = fp[t00] * w00 + fp[t01] * w01 + fp[t10] * w10 + fp[t11] * w11;
    acc += s * fp[q];
  }
  part[cg][px] = acc;
  __syncthreads();
  if (cg == 0) {
    float s = (part[0][px] + part[1][px]) + (part[2][px] + part[3][px]);
    corr[b * HW + q] = s * 0.0078125f;
  }
}

// One conv layer via split-f16 MFMA: acc += Wh*xh + Wh*xl + Wl*xh, f32 accum.
template<bool LAYER1, bool LAST>
__device__ __forceinline__ void conv_layer(float* buf, const f16* wh, const f16* wl,
                                           const float* bias, const float* w1full,
                                           float* og, int wv, int l15, int l4) {
  f32x4 acc[2][4];
  #pragma unroll
  for (int r = 0; r < 2; ++r)
    #pragma unroll
    for (int c = 0; c < 4; ++c) acc[r][c] = (f32x4){0.f, 0.f, 0.f, 0.f};

  for (int k0 = 0; k0 < 128; k0 += 32) {
    f16x8 ah0 = *(const f16x8*)&wh[(wv * 32 + l15) * 128 + k0 + l4 * 8];
    f16x8 ah1 = *(const f16x8*)&wh[(wv * 32 + 16 + l15) * 128 + k0 + l4 * 8];
    f16x8 al0 = *(const f16x8*)&wl[(wv * 32 + l15) * 128 + k0 + l4 * 8];
    f16x8 al1 = *(const f16x8*)&wl[(wv * 32 + 16 + l15) * 128 + k0 + l4 * 8];
    #pragma unroll
    for (int c = 0; c < 4; ++c) {
      const float* bp = &buf[(c * 16 + l15) * 132 + k0 + l4 * 8];
      f32x4 v0 = *(const f32x4*)bp;
      f32x4 v1 = *(const f32x4*)(bp + 4);
      f16x8 bh, bl;
      #pragma unroll
      for (int i = 0; i < 4; ++i) {
        float x = v0[i]; f16 h = (f16)x; bh[i] = h; bl[i] = (f16)(x - (float)h);
        float x2 = v1[i]; f16 h2 = (f16)x2; bh[4 + i] = h2; bl[4 + i] = (f16)(x2 - (float)h2);
      }
      acc[0][c] = __builtin_amdgcn_mfma_f32_16x16x32_f16(ah0, bh, acc[0][c], 0, 0, 0);
      acc[0][c] = __builtin_amdgcn_mfma_f32_16x16x32_f16(ah0, bl, acc[0][c], 0, 0, 0);
      acc[0][c] = __builtin_amdgcn_mfma_f32_16x16x32_f16(al0, bh, acc[0][c], 0, 0, 0);
      acc[1][c] = __builtin_amdgcn_mfma_f32_16x16x32_f16(ah1, bh, acc[1][c], 0, 0, 0);
      acc[1][c] = __builtin_amdgcn_mfma_f32_16x16x32_f16(ah1, bl, acc[1][c], 0, 0, 0);
      acc[1][c] = __builtin_amdgcn_mfma_f32_16x16x32_f16(al1, bh, acc[1][c], 0, 0, 0);
    }
  }
  __syncthreads();
  #pragma unroll
  for (int r = 0; r < 2; ++r) {
    int ob = wv * 32 + r * 16 + l4 * 4;
    f32x4 bb = *(const f32x4*)&bias[ob];
    float w1c[4][3];
    if (LAYER1) {
      #pragma unroll
      for (int e = 0; e < 4; ++e) {
        w1c[e][0] = w1full[(ob + e) * 131 + 0];
        w1c[e][1] = w1full[(ob + e) * 131 + 1];
        w1c[e][2] = w1full[(ob + e) * 131 + 2];
      }
    }
    #pragma unroll
    for (int c = 0; c < 4; ++c) {
      int p = c * 16 + l15;
      float s0 = 0.f, s1 = 0.f, s2 = 0.f;
      if (LAYER1) { s0 = buf[p * 132 + 128]; s1 = buf[p * 132 + 129]; s2 = buf[p * 132 + 130]; }
      f32x4 yv;
      #pragma unroll
      for (int e = 0; e < 4; ++e) {
        float y = acc[r][c][e] + bb[e];
        if (LAYER1) y += w1c[e][0] * s0 + w1c[e][1] * s1 + w1c[e][2] * s2;
        y = (y >= 0.f) ? y : 0.1f * y;
        yv[e] = y;
        if (LAST) og[(size_t)(ob + e) * HW + p] = y;
      }
      if (!LAST) *(f32x4*)&buf[p * 132 + ob] = yv;
    }
  }
  __syncthreads();
}

// Fused 3-layer 1x1 conv. Block = 256 thr, tile = 128 outch x 64 px.
__global__ __launch_bounds__(256) void k_conv(const float* __restrict__ f3t,
                                              const int* __restrict__ nn_idx,
                                              const float* __restrict__ uv,
                                              const float* __restrict__ corr,
                                              const f16* __restrict__ whl,
                                              const float* __restrict__ w1full,
                                              const float* __restrict__ b1,
                                              const float* __restrict__ b2,
                                              const float* __restrict__ b3,
                                              float* __restrict__ out) {
  __shared__ float buf[64 * 132];
  __shared__ int js[64];
  int blk = blockIdx.x;              // 768 = 2 * 384
  int b = blk / 384;
  int q0 = (blk - b * 384) * 64;
  int tid = threadIdx.x;
  int lane = tid & 63, wv = tid >> 6;
  int l15 = lane & 15, l4 = lane >> 4;

  if (tid < 64) js[tid] = nn_idx[b * HW + q0 + tid];
  __syncthreads();
  for (int i = tid; i < 64 * 33; i += 256) {
    int row = i / 33, c = i - row * 33;
    if (c < 32) {
      *(f32x4*)&buf[row * 132 + c * 4] =
          *(const f32x4*)&f3t[((size_t)(b * NPTS + js[row])) * CH + c * 4];
    } else {
      int q = q0 + row;
      int j = js[row];
      float u = uv[b * 2 * NPTS + j], v = uv[b * 2 * NPTS + NPTS + j];
      float xq = (float)(q % WID), yq = (float)(q / WID);
      f32x4 t = {u - xq, v - yq, corr[b * HW + q], 0.f};
      *(f32x4*)&buf[row * 132 + 128] = t;
    }
  }
  __syncthreads();

  float* og = out + (size_t)b * CH * HW + q0;
  conv_layer<true,  false>(buf, whl + 0 * 16384, whl + 1 * 16384, b1, w1full, og, wv, l15, l4);
  conv_layer<false, false>(buf, whl + 2 * 16384, whl + 3 * 16384, b2, nullptr, og, wv, l15, l4);
  conv_layer<false, true >(buf, whl + 4 * 16384, whl + 5 * 16384, b3, nullptr, og, wv, l15, l4);
}

extern "C" void kernel_launch(void* const* d_in, const int* in_sizes, int n_in,
                              void* d_out, int out_size, void* d_ws, size_t ws_size,
                              hipStream_t stream) {
  const float* uv     = (const float*)d_in[0];
  const float* feat2d = (const float*)d_in[1];
  const float* feat3d = (const float*)d_in[2];
  const float* w1 = (const float*)d_in[3];
  const float* b1 = (const float*)d_in[4];
  const float* w2 = (const float*)d_in[5];
  const float* b2 = (const float*)d_in[6];
  const float* w3 = (const float*)d_in[7];
  const float* b3 = (const float*)d_in[8];
  float* out = (float*)d_out;
  char* ws = (char*)d_ws;
  int*    nn_idx  = (int*)(ws + OFF_NNIDX);
  float*  corr    = (float*)(ws + OFF_CORR);
  float*  f3t     = (float*)(ws + OFF_F3T);
  f16*    whl     = (f16*)(ws + OFF_WHL);
  float4* pts     = (float4*)(ws + OFF_PTS);   // aliases corr region (dead
  int*    offs    = (int*)(ws + OFF_OFFS);     // before k_corr writes corr)

  k_prep_w<<<dim3(192), dim3(256), 0, stream>>>(w1, w2, w3, whl);
  k_tr    <<<dim3(512), dim3(256), 0, stream>>>(feat3d, f3t);
  k_bin   <<<dim3(2),   dim3(512), 0, stream>>>(uv, pts, offs);
  k_nnq   <<<dim3(384), dim3(128), 0, stream>>>(pts, offs, nn_idx);
  k_corr  <<<dim3(768), dim3(256), 0, stream>>>(nn_idx, uv, feat2d, corr);
  k_conv  <<<dim3(768), dim3(256), 0, stream>>>(f3t, nn_idx, uv, corr, whl, w1,
                                                b1, b2, b3, out);
}

// Round 20
// 88.612 us; speedup vs baseline: 1.8267x; 1.1809x over previous
//
#include <hip/hip_runtime.h>

typedef _Float16 f16;
typedef f16  f16x8 __attribute__((ext_vector_type(8)));
typedef float f32x4 __attribute__((ext_vector_type(4)));

#define NPTS 4096
#define HW   24576
#define WID  192
#define CH   128
#define NCX  24
#define NCY  16
#define NCELL 384
#define EPS  0.15f

// ---- workspace layout (bytes) ----  (total 8978432, proven-safe size)
#define OFF_NNIDX   (0u)           // int[49152]
#define OFF_CORR    (196608u)      // region reused for pts/offs
#define OFF_F3T     (4587520u)     // float[8192*128]
#define OFF_WHL     (8781824u)     // f16[3][2][128][128]
#define OFF_PTS     (OFF_CORR)             // float4[2][4096] = 131072 B
#define OFF_OFFS    (OFF_CORR + 131072u)   // int[2][385]     = 3080 B

__device__ __forceinline__ int cell_of(float u, float v) {
  int cx = (int)(u * 0.125f); cx = min(max(cx, 0), NCX - 1);
  int cy = (int)(v * 0.125f); cy = min(max(cy, 0), NCY - 1);
  return cy * NCX + cx;
}

// Fused prep: blocks 0..95 weight hi/lo split; 96..607 feat3d transpose;
// 608..609 point binning (parallel Hillis-Steele prefix scan).
__global__ __launch_bounds__(512) void k_prep(const float* __restrict__ w1,
                                              const float* __restrict__ w2,
                                              const float* __restrict__ w3,
                                              const float* __restrict__ feat3d,
                                              const float* __restrict__ uv,
                                              f16* __restrict__ whl,
                                              float* __restrict__ f3t,
                                              float4* __restrict__ pts,
                                              int* __restrict__ offs) {
#pragma clang fp contract(off)
  __shared__ __align__(16) char smem[8448];
  int blk = blockIdx.x;
  int tid = threadIdx.x;
  if (blk < 96) {               // ---- weight split: 96*512 = 49152
    int i = blk * 512 + tid;
    int layer = i >> 14;
    int r = i & 16383;
    int o = r >> 7, k = r & 127;
    float v;
    if (layer == 0)      v = w1[o * 131 + 3 + k];
    else if (layer == 1) v = w2[o * 128 + k];
    else                 v = w3[o * 128 + k];
    f16 h = (f16)v;
    f16 l = (f16)(v - (float)h);
    whl[(layer * 2 + 0) * 16384 + r] = h;
    whl[(layer * 2 + 1) * 16384 + r] = l;
  } else if (blk < 608) {       // ---- transpose tile 32c x 64p
    float (*tile)[65] = (float (*)[65])smem;
    int t = blk - 96;           // 0..511
    int b = t >> 8;
    int r = t & 255;
    int cg = r >> 6, pg = r & 63;
    int c0 = cg * 32, p0 = pg * 64;
    {
      int p = tid & 63;
      int c = tid >> 6;         // 0..7, step 8
      #pragma unroll
      for (int cc = 0; cc < 32; cc += 8)
        tile[c + cc][p] = feat3d[(size_t)(b * CH + c0 + c + cc) * NPTS + p0 + p];
    }
    __syncthreads();
    {
      int c = tid & 31;
      int p = tid >> 5;         // 0..15, step 16
      #pragma unroll
      for (int pp = 0; pp < 64; pp += 16)
        f3t[(size_t)(b * NPTS + p0 + p + pp) * CH + c0 + c] = tile[c][p + pp];
    }
  } else {                      // ---- binning (2 blocks)
    int* cnt  = (int*)smem;                 // [NCELL]
    int* base = cnt + NCELL;                // [NCELL+1]
    int* sc   = base + NCELL + 1;           // [512]
    int b = blk - 608;
    const float* up = uv + b * 2 * NPTS;
    for (int i = tid; i < NCELL; i += 512) cnt[i] = 0;
    __syncthreads();
    for (int p = tid; p < NPTS; p += 512)
      atomicAdd(&cnt[cell_of(up[p], up[NPTS + p])], 1);
    __syncthreads();
    sc[tid] = (tid < NCELL) ? cnt[tid] : 0;
    __syncthreads();
    #pragma unroll
    for (int off = 1; off < 512; off <<= 1) {
      int val = (tid >= off) ? sc[tid - off] : 0;
      __syncthreads();
      sc[tid] += val;
      __syncthreads();
    }
    if (tid < NCELL) base[tid + 1] = sc[tid];
    if (tid == 0) base[0] = 0;
    __syncthreads();
    for (int i = tid; i <= NCELL; i += 512) offs[b * (NCELL + 1) + i] = base[i];
    for (int i = tid; i < NCELL; i += 512) cnt[i] = base[i];
    __syncthreads();
    for (int p = tid; p < NPTS; p += 512) {
      float u = up[p], v = up[NPTS + p];
      int pos = atomicAdd(&cnt[cell_of(u, v)], 1);
      float uu = u * u;   asm volatile("" : "+v"(uu));
      float vv = v * v;   asm volatile("" : "+v"(vv));
      float ss = uu + vv; asm volatile("" : "+v"(ss));
      float4 t; t.x = u; t.y = v; t.z = ss; t.w = __int_as_float(p);
      pts[b * NPTS + pos] = t;
    }
  }
}

// NN query: one WAVE per 8x8 pixel tile. Ring scan; bit-exact pinned ref d2
// for candidates; lexicographic (d2,idx) min == first-index strict-<.
__global__ __launch_bounds__(128) void k_nnq(const float4* __restrict__ pts,
                                             const int* __restrict__ offs,
                                             int* __restrict__ nn_idx) {
#pragma clang fp contract(off)
  int tile = blockIdx.x * 2 + (threadIdx.x >> 6);   // 768 tiles
  int lane = threadIdx.x & 63;
  int b = tile / NCELL;
  int t = tile - b * NCELL;
  int ty = t / NCX, tx = t - ty * NCX;
  int px = tx * 8 + (lane & 7);
  int py = ty * 8 + (lane >> 3);
  float xq = (float)px, yq = (float)py;
  float ssg = xq * xq + yq * yq;
  const float4* P = pts + b * NPTS;
  const int* O = offs + b * (NCELL + 1);

  float m = 3.4e38f;
  float bestr = 3.4e38f; int bir = 0x7fffffff;

  for (int R = 0; R < 24; ++R) {
    if (R > 0) {
      float mm = m;
      #pragma unroll
      for (int o = 32; o; o >>= 1) mm = fmaxf(mm, __shfl_xor(mm, o));
      float bound = 64.f * (float)((R - 1) * (R - 1));
      if (bound > mm + EPS) break;
    }
    int x0 = max(0, tx - R), x1 = min(NCX - 1, tx + R);
    int y0 = max(0, ty - R), y1 = min(NCY - 1, ty + R);
    for (int cy = y0; cy <= y1; ++cy) {
      for (int cx = x0; cx <= x1; ++cx) {
        int cd = max(abs(cx - tx), abs(cy - ty));
        if (cd != R) continue;
        int c = cy * NCX + cx;
        int s = O[c], e = O[c + 1];
        for (int i = s; i < e; ++i) {
          float4 pt = P[i];
          float dx = xq - pt.x, dy = yq - pt.y;
          float d2a = fmaf(dy, dy, dx * dx);
          m = fminf(m, d2a);
          if (d2a <= m + EPS) {
            float xu = xq * pt.x;                       asm volatile("" : "+v"(xu));
            float qp = __builtin_fmaf(yq, pt.y, xu);    asm volatile("" : "+v"(qp));
            float tq = 2.0f * qp;                       asm volatile("" : "+v"(tq));
            float t1 = ssg - tq;                        asm volatile("" : "+v"(t1));
            float d2 = t1 + pt.z;                       asm volatile("" : "+v"(d2));
            int pi = __float_as_int(pt.w);
            if (d2 < bestr || (d2 == bestr && pi < bir)) { bestr = d2; bir = pi; }
          }
        }
      }
    }
  }
  nn_idx[b * HW + py * WID + px] = bir;
}

// One conv layer via split-f16 MFMA: acc += Wh*xh + Wh*xl + Wl*xh, f32 accum.
template<bool LAYER1, bool LAST>
__device__ __forceinline__ void conv_layer(float* buf, const f16* wh, const f16* wl,
                                           const float* bias, const float* w1full,
                                           float* og, int wv, int l15, int l4) {
  f32x4 acc[2][4];
  #pragma unroll
  for (int r = 0; r < 2; ++r)
    #pragma unroll
    for (int c = 0; c < 4; ++c) acc[r][c] = (f32x4){0.f, 0.f, 0.f, 0.f};

  for (int k0 = 0; k0 < 128; k0 += 32) {
    f16x8 ah0 = *(const f16x8*)&wh[(wv * 32 + l15) * 128 + k0 + l4 * 8];
    f16x8 ah1 = *(const f16x8*)&wh[(wv * 32 + 16 + l15) * 128 + k0 + l4 * 8];
    f16x8 al0 = *(const f16x8*)&wl[(wv * 32 + l15) * 128 + k0 + l4 * 8];
    f16x8 al1 = *(const f16x8*)&wl[(wv * 32 + 16 + l15) * 128 + k0 + l4 * 8];
    #pragma unroll
    for (int c = 0; c < 4; ++c) {
      const float* bp = &buf[(c * 16 + l15) * 132 + k0 + l4 * 8];
      f32x4 v0 = *(const f32x4*)bp;
      f32x4 v1 = *(const f32x4*)(bp + 4);
      f16x8 bh, bl;
      #pragma unroll
      for (int i = 0; i < 4; ++i) {
        float x = v0[i]; f16 h = (f16)x; bh[i] = h; bl[i] = (f16)(x - (float)h);
        float x2 = v1[i]; f16 h2 = (f16)x2; bh[4 + i] = h2; bl[4 + i] = (f16)(x2 - (float)h2);
      }
      acc[0][c] = __builtin_amdgcn_mfma_f32_16x16x32_f16(ah0, bh, acc[0][c], 0, 0, 0);
      acc[0][c] = __builtin_amdgcn_mfma_f32_16x16x32_f16(ah0, bl, acc[0][c], 0, 0, 0);
      acc[0][c] = __builtin_amdgcn_mfma_f32_16x16x32_f16(al0, bh, acc[0][c], 0, 0, 0);
      acc[1][c] = __builtin_amdgcn_mfma_f32_16x16x32_f16(ah1, bh, acc[1][c], 0, 0, 0);
      acc[1][c] = __builtin_amdgcn_mfma_f32_16x16x32_f16(ah1, bl, acc[1][c], 0, 0, 0);
      acc[1][c] = __builtin_amdgcn_mfma_f32_16x16x32_f16(al1, bh, acc[1][c], 0, 0, 0);
    }
  }
  __syncthreads();
  #pragma unroll
  for (int r = 0; r < 2; ++r) {
    int ob = wv * 32 + r * 16 + l4 * 4;
    f32x4 bb = *(const f32x4*)&bias[ob];
    float w1c[4][3];
    if (LAYER1) {
      #pragma unroll
      for (int e = 0; e < 4; ++e) {
        w1c[e][0] = w1full[(ob + e) * 131 + 0];
        w1c[e][1] = w1full[(ob + e) * 131 + 1];
        w1c[e][2] = w1full[(ob + e) * 131 + 2];
      }
    }
    #pragma unroll
    for (int c = 0; c < 4; ++c) {
      int p = c * 16 + l15;
      float s0 = 0.f, s1 = 0.f, s2 = 0.f;
      if (LAYER1) { s0 = buf[p * 132 + 128]; s1 = buf[p * 132 + 129]; s2 = buf[p * 132 + 130]; }
      f32x4 yv;
      #pragma unroll
      for (int e = 0; e < 4; ++e) {
        float y = acc[r][c][e] + bb[e];
        if (LAYER1) y += w1c[e][0] * s0 + w1c[e][1] * s1 + w1c[e][2] * s2;
        y = (y >= 0.f) ? y : 0.1f * y;
        yv[e] = y;
        if (LAST) og[(size_t)(ob + e) * HW + p] = y;
      }
      if (!LAST) *(f32x4*)&buf[p * 132 + ob] = yv;
    }
  }
  __syncthreads();
}

// Fused corr + 3-layer conv. Block = 256 thr, tile = 128 outch x 64 px.
// corr phase: identical thread mapping / accumulation order as the verified
// k_corr (cg=tid>>6, px=tid&63, ascending-c, pairwise group combine).
__global__ __launch_bounds__(256) void k_conv(const float* __restrict__ f3t,
                                              const int* __restrict__ nn_idx,
                                              const float* __restrict__ uv,
                                              const float* __restrict__ feat2d,
                                              const f16* __restrict__ whl,
                                              const float* __restrict__ w1full,
                                              const float* __restrict__ b1,
                                              const float* __restrict__ b2,
                                              const float* __restrict__ b3,
                                              float* __restrict__ out) {
  __shared__ float buf[64 * 132];
  __shared__ int js[64];
  __shared__ float part[4][64];
  __shared__ float corrs[64];
  int blk = blockIdx.x;              // 768 = 2 * 384
  int b = blk / 384;
  int q0 = (blk - b * 384) * 64;
  int tid = threadIdx.x;
  int lane = tid & 63, wv = tid >> 6;
  int l15 = lane & 15, l4 = lane >> 4;

  if (tid < 64) js[tid] = nn_idx[b * HW + q0 + tid];
  __syncthreads();

  { // ---- corr phase ----
    int cg = tid >> 6, cpx = tid & 63;
    int q = q0 + cpx;
    int j = js[cpx];
    float u = uv[b * 2 * NPTS + j], v = uv[b * 2 * NPTS + NPTS + j];
    float x0f = floorf(u), y0f = floorf(v);
    float wx = u - x0f, wy = v - y0f;
    int x0 = (int)x0f; x0 = min(max(x0, 0), WID - 1);
    int x1 = min(x0 + 1, WID - 1);
    int y0 = (int)y0f; y0 = min(max(y0, 0), 127);
    int y1 = min(y0 + 1, 127);
    int t00 = y0 * WID + x0, t01 = y0 * WID + x1;
    int t10 = y1 * WID + x0, t11 = y1 * WID + x1;
    float w00 = (1.f - wx) * (1.f - wy), w01 = wx * (1.f - wy);
    float w10 = (1.f - wx) * wy,         w11 = wx * wy;
    const float* fpb = feat2d + (size_t)(b * CH + cg * 32) * HW;
    float acc = 0.f;
    #pragma unroll 8
    for (int i = 0; i < 32; ++i) {
      const float* fp = fpb + (size_t)i * HW;
      float s = fp[t00] * w00 + fp[t01] * w01 + fp[t10] * w10 + fp[t11] * w11;
      acc += s * fp[q];
    }
    part[cg][cpx] = acc;
    __syncthreads();
    if (cg == 0) {
      float s = (part[0][cpx] + part[1][cpx]) + (part[2][cpx] + part[3][cpx]);
      corrs[cpx] = s * 0.0078125f;
    }
    __syncthreads();
  }

  for (int i = tid; i < 64 * 33; i += 256) {
    int row = i / 33, c = i - row * 33;
    if (c < 32) {
      *(f32x4*)&buf[row * 132 + c * 4] =
          *(const f32x4*)&f3t[((size_t)(b * NPTS + js[row])) * CH + c * 4];
    } else {
      int q = q0 + row;
      int j = js[row];
      float u = uv[b * 2 * NPTS + j], v = uv[b * 2 * NPTS + NPTS + j];
      float xq = (float)(q % WID), yq = (float)(q / WID);
      f32x4 t = {u - xq, v - yq, corrs[row], 0.f};
      *(f32x4*)&buf[row * 132 + 128] = t;
    }
  }
  __syncthreads();

  float* og = out + (size_t)b * CH * HW + q0;
  conv_layer<true,  false>(buf, whl + 0 * 16384, whl + 1 * 16384, b1, w1full, og, wv, l15, l4);
  conv_layer<false, false>(buf, whl + 2 * 16384, whl + 3 * 16384, b2, nullptr, og, wv, l15, l4);
  conv_layer<false, true >(buf, whl + 4 * 16384, whl + 5 * 16384, b3, nullptr, og, wv, l15, l4);
}

extern "C" void kernel_launch(void* const* d_in, const int* in_sizes, int n_in,
                              void* d_out, int out_size, void* d_ws, size_t ws_size,
                              hipStream_t stream) {
  const float* uv     = (const float*)d_in[0];
  const float* feat2d = (const float*)d_in[1];
  const float* feat3d = (const float*)d_in[2];
  const float* w1 = (const float*)d_in[3];
  const float* b1 = (const float*)d_in[4];
  const float* w2 = (const float*)d_in[5];
  const float* b2 = (const float*)d_in[6];
  const float* w3 = (const float*)d_in[7];
  const float* b3 = (const float*)d_in[8];
  float* out = (float*)d_out;
  char* ws = (char*)d_ws;
  int*    nn_idx  = (int*)(ws + OFF_NNIDX);
  float*  f3t     = (float*)(ws + OFF_F3T);
  f16*    whl     = (f16*)(ws + OFF_WHL);
  float4* pts     = (float4*)(ws + OFF_PTS);
  int*    offs    = (int*)(ws + OFF_OFFS);

  k_prep<<<dim3(610), dim3(512), 0, stream>>>(w1, w2, w3, feat3d, uv, whl, f3t,
                                              pts, offs);
  k_nnq <<<dim3(384), dim3(128), 0, stream>>>(pts, offs, nn_idx);
  k_conv<<<dim3(768), dim3(256), 0, stream>>>(f3t, nn_idx, uv, feat2d, whl, w1,
                                              b1, b2, b3, out);
}